// Round 15
// baseline (313.437 us; speedup 1.0000x reference)
//
#include <hip/hip_runtime.h>
#include <hip/hip_bf16.h>
#include <stdint.h>

#define TOKENS 4096
#define HDIM   1024
#define FDIM   2048
#define NEXP   8
#define NSLOTS (2 * TOKENS)
#define SLOTPAD (NSLOTS + 256)
#define RISKY_CAP 256
#define FLAG_THR 6e-3f

typedef __attribute__((ext_vector_type(4))) float        f32x4v;
typedef __attribute__((ext_vector_type(4))) unsigned int u32x4v;
typedef __attribute__((ext_vector_type(8))) _Float16     f16x8v;

__device__ __forceinline__ unsigned short f2h(float f) {
  _Float16 h = (_Float16)f;
  union { _Float16 h; unsigned short u; } x; x.h = h; return x.u;
}

__device__ __forceinline__ void gload16(void* lds, const void* g) {
  __builtin_amdgcn_global_load_lds(
      reinterpret_cast<const __attribute__((address_space(1))) uint32_t*>(
          reinterpret_cast<uintptr_t>(g)),
      reinterpret_cast<__attribute__((address_space(3))) uint32_t*>(
          reinterpret_cast<uintptr_t>(lds)),
      16, 0, 0);
}

// ---------------- transpose tile: [R][C] f32 -> [C][R] f16, one 64x64 tile ----------------
__device__ __forceinline__ void transpose_tile_v2(const float* __restrict__ ip,
                                                  unsigned short* __restrict__ op,
                                                  int R, int C, int r0, int c0) {
  __shared__ unsigned short tile[64][70];
  const int t = threadIdx.x;
  const int cp = (t & 15) * 4;
  const int rp = (t >> 4) * 2;
#pragma unroll
  for (int p = 0; p < 2; ++p) {
    const int r = rp + p * 32;
    f32x4v v0 = *(const f32x4v*)(ip + (size_t)(r0 + r) * C + c0 + cp);
    f32x4v v1 = *(const f32x4v*)(ip + (size_t)(r0 + r + 1) * C + c0 + cp);
#pragma unroll
    for (int j = 0; j < 4; ++j)
      *(uint32_t*)&tile[cp + j][r] = (uint32_t)f2h(v0[j]) | ((uint32_t)f2h(v1[j]) << 16);
  }
  __syncthreads();
  const int c = t >> 2, rc = (t & 3) * 16;
  uint32_t q[8];
#pragma unroll
  for (int j = 0; j < 8; ++j) q[j] = *(uint32_t*)&tile[c][rc + j * 2];
  unsigned short* o = op + (size_t)(c0 + c) * R + r0 + rc;
  u32x4v s0, s1;
  s0[0] = q[0]; s0[1] = q[1]; s0[2] = q[2]; s0[3] = q[3];
  s1[0] = q[4]; s1[1] = q[5]; s1[2] = q[6]; s1[3] = q[7];
  *(u32x4v*)o = s0;
  *(u32x4v*)(o + 8) = s1;
}

// ---------------- prep0: gw1 transpose + zero rcnt ----------------
__global__ __launch_bounds__(256)
void k_prep0(const float* __restrict__ gw1, unsigned short* __restrict__ og1,
             int* __restrict__ rcnt) {
  if (blockIdx.x == 256) {
    if (threadIdx.x == 0) rcnt[0] = 0;
    return;
  }
  transpose_tile_v2(gw1, og1, 1024, 1024, (blockIdx.x >> 4) * 64, (blockIdx.x & 15) * 64);
}

// ---------------- fused: gate GEMM (f32 X in, emits Xh) + w13/w2 transposes ----------
#define NB_GATE 512
#define NB_W13  8192
#define NB_W2   4096
__global__ __launch_bounds__(256)
void k_fused(const float* __restrict__ X, unsigned short* __restrict__ Xh,
             const float* __restrict__ w1, const float* __restrict__ w3,
             unsigned short* __restrict__ o1, unsigned short* __restrict__ o3,
             const float* __restrict__ w2, unsigned short* __restrict__ o2,
             const unsigned short* __restrict__ gw1T, const float* __restrict__ gb1,
             unsigned short* __restrict__ Gh) {
  const int id = blockIdx.x;
  const int t = threadIdx.x;
  if (id < NB_GATE) {
    __shared__ unsigned short lA[128 * 64];
    __shared__ unsigned short lB[64 * 64];
    const int n0 = (id & 15) * 64, m0 = (id >> 4) * 128;
    const bool writeX = (id & 15) == 0;   // one n-tile per m-tile also emits Xh
    const int lane = t & 63, wv = t >> 6;

    const unsigned short* bp[2];
#pragma unroll
    for (int i = 0; i < 2; ++i) {
      const int gi = wv * 2 + i;
      const int row = gi * 8 + (lane >> 3);
      const int cs = (lane & 7) ^ (row & 7);
      bp[i] = gw1T + (size_t)(n0 + row) * HDIM + cs * 8;
    }

    f32x4v acc[4][2];
#pragma unroll
    for (int m = 0; m < 4; ++m)
#pragma unroll
      for (int n = 0; n < 2; ++n) acc[m][n] = (f32x4v){0.f, 0.f, 0.f, 0.f};

    const int wr = (wv >> 1) * 64, wc = (wv & 1) * 32;

    for (int k0 = 0; k0 < HDIM; k0 += 64) {
#pragma unroll
      for (int p = 0; p < 4; ++p) {
        const int ga = p * 256 + t;
        const int r = ga >> 3, c = ga & 7;
        const float* s = X + (size_t)(m0 + r) * HDIM + k0 + c * 8;
        f32x4v v0 = *(const f32x4v*)s;
        f32x4v v1 = *(const f32x4v*)(s + 4);
        u32x4v pk;
        pk[0] = (uint32_t)f2h(v0[0]) | ((uint32_t)f2h(v0[1]) << 16);
        pk[1] = (uint32_t)f2h(v0[2]) | ((uint32_t)f2h(v0[3]) << 16);
        pk[2] = (uint32_t)f2h(v1[0]) | ((uint32_t)f2h(v1[1]) << 16);
        pk[3] = (uint32_t)f2h(v1[2]) | ((uint32_t)f2h(v1[3]) << 16);
        *(u32x4v*)&lA[r * 64 + ((c ^ (r & 7)) * 8)] = pk;
        if (writeX) *(u32x4v*)(Xh + (size_t)(m0 + r) * HDIM + k0 + c * 8) = pk;
      }
#pragma unroll
      for (int i = 0; i < 2; ++i) gload16(lB + (wv * 2 + i) * 512, bp[i] + k0);
      __syncthreads();
#pragma unroll
      for (int kk = 0; kk < 2; ++kk) {
        const int ch = kk * 4 + (lane >> 4);
        f16x8v af[4];
#pragma unroll
        for (int m = 0; m < 4; ++m) {
          const int r = wr + m * 16 + (lane & 15);
          af[m] = *(const f16x8v*)(lA + r * 64 + (ch ^ (r & 7)) * 8);
        }
#pragma unroll
        for (int n = 0; n < 2; ++n) {
          const int r = wc + n * 16 + (lane & 15);
          f16x8v b = *(const f16x8v*)(lB + r * 64 + (ch ^ (r & 7)) * 8);
#pragma unroll
          for (int m = 0; m < 4; ++m)
            acc[m][n] = __builtin_amdgcn_mfma_f32_16x16x32_f16(af[m], b, acc[m][n], 0, 0, 0);
        }
      }
      __syncthreads();
    }
#pragma unroll
    for (int m = 0; m < 4; ++m)
#pragma unroll
      for (int n = 0; n < 2; ++n)
#pragma unroll
        for (int q = 0; q < 4; ++q) {
          const int row = m0 + wr + m * 16 + ((lane >> 4) << 2) + q;
          const int col = n0 + wc + n * 16 + (lane & 15);
          float x = acc[m][n][q] + gb1[col];
          Gh[(size_t)row * 1024 + col] = f2h(x > 0.f ? x : expm1f(x));
        }
    return;
  }
  int b = id - NB_GATE;
  if (b < NB_W13) {
    const int bx = b & 31, by = (b >> 5) & 15, bz = b >> 9;
    const int e = bz & 7, which = bz >> 3;
    const size_t mat = (size_t)1024 * 2048;
    transpose_tile_v2((which ? w3 : w1) + (size_t)e * mat,
                      (which ? o3 : o1) + (size_t)e * mat,
                      1024, 2048, by * 64, bx * 64);
    return;
  }
  b -= NB_W13;
  {
    const int bx = b & 15, by = (b >> 4) & 31, e = b >> 9;
    const size_t mat = (size_t)2048 * 1024;
    transpose_tile_v2(w2 + (size_t)e * mat, o2 + (size_t)e * mat,
                      2048, 1024, by * 64, bx * 64);
  }
}

// ---------------- router logits (fp32 accum over f16 G) + fused risk flag ----------------
__global__ void k_logits(const unsigned short* __restrict__ Gh, const float* __restrict__ gw2,
                         const float* __restrict__ gb2, float* __restrict__ Lg,
                         int* __restrict__ risky, int* __restrict__ rcnt) {
  const int lane = threadIdx.x & 63, wv = threadIdx.x >> 6;
  const int tok = blockIdx.x * 4 + wv;
  const unsigned short* g = Gh + (size_t)tok * 1024 + lane * 16;
  f16x8v g0 = *(const f16x8v*)g;
  f16x8v g1 = *(const f16x8v*)(g + 8);
  float gv[16];
#pragma unroll
  for (int j = 0; j < 8; ++j) { gv[j] = (float)g0[j]; gv[8 + j] = (float)g1[j]; }
  float acc[8];
#pragma unroll
  for (int j = 0; j < 8; ++j) acc[j] = 0.f;
#pragma unroll
  for (int u = 0; u < 16; ++u) {
    const float* wrow = gw2 + (size_t)(lane * 16 + u) * 8;
    f32x4v w0 = *(const f32x4v*)wrow;
    f32x4v w1 = *(const f32x4v*)(wrow + 4);
#pragma unroll
    for (int j = 0; j < 4; ++j) {
      acc[j]     += gv[u] * w0[j];
      acc[j + 4] += gv[u] * w1[j];
    }
  }
#pragma unroll
  for (int s = 1; s < 64; s <<= 1)
#pragma unroll
    for (int j = 0; j < 8; ++j) acc[j] += __shfl_xor(acc[j], s, 64);
  if (lane == 0) {
    float l[8];
#pragma unroll
    for (int j = 0; j < 8; ++j) { l[j] = acc[j] + gb2[j]; Lg[(size_t)tok * 8 + j] = l[j]; }
    int i0 = 0; float v0 = l[0];
#pragma unroll
    for (int j = 1; j < 8; ++j) if (l[j] > v0) { v0 = l[j]; i0 = j; }
    int i1 = (i0 == 0) ? 1 : 0; float v1 = l[i1];
#pragma unroll
    for (int j = 0; j < 8; ++j) if (j != i0 && l[j] > v1) { v1 = l[j]; i1 = j; }
    float v2 = -1e30f;
#pragma unroll
    for (int j = 0; j < 8; ++j) if (j != i0 && j != i1 && l[j] > v2) v2 = l[j];
    if (v1 - v2 < FLAG_THR) {
      const int pos = atomicAdd(rcnt, 1);
      if (pos < RISKY_CAP) risky[pos] = tok;
    }
  }
}

// ---------------- merged fixup: exact fp32 gate MLP + logits for risky tokens ----------
__global__ __launch_bounds__(1024)
void k_fixup(const float* __restrict__ X, const float* __restrict__ gw1,
             const float* __restrict__ gb1, const float* __restrict__ gw2,
             const float* __restrict__ gb2, const int* __restrict__ risky,
             const int* __restrict__ rcnt, float* __restrict__ Lg) {
  __shared__ float xs[1024];
  __shared__ float gs[1024];
  __shared__ float part[16][8];
  int n = *rcnt; if (n > RISKY_CAP) n = RISKY_CAP;
  const int idx = blockIdx.x;
  if (idx >= n) return;
  const int tok = risky[idx];
  const int t = threadIdx.x, lane = t & 63, wv = t >> 6;
  xs[t] = X[(size_t)tok * 1024 + t];
  __syncthreads();
  // gs[t] = ELU(dot(xs, gw1[:, t]) + gb1[t]); columns coalesced across threads
  {
    const float* wp = gw1 + t;
    float a0 = 0.f, a1 = 0.f, a2 = 0.f, a3 = 0.f;
    for (int k = 0; k < 1024; k += 4) {
      a0 += xs[k]     * wp[(size_t)k * 1024];
      a1 += xs[k + 1] * wp[(size_t)(k + 1) * 1024];
      a2 += xs[k + 2] * wp[(size_t)(k + 2) * 1024];
      a3 += xs[k + 3] * wp[(size_t)(k + 3) * 1024];
    }
    const float v = (a0 + a1) + (a2 + a3) + gb1[t];
    gs[t] = v > 0.f ? v : expm1f(v);
  }
  __syncthreads();
  // logits: thread t covers k=t
  float lacc[8];
  {
    const float gv = gs[t];
    const float* w = gw2 + (size_t)t * 8;
#pragma unroll
    for (int e = 0; e < 8; ++e) lacc[e] = gv * w[e];
  }
#pragma unroll
  for (int s = 1; s < 64; s <<= 1)
#pragma unroll
    for (int e = 0; e < 8; ++e) lacc[e] += __shfl_xor(lacc[e], s, 64);
  if (lane == 0) {
#pragma unroll
    for (int e = 0; e < 8; ++e) part[wv][e] = lacc[e];
  }
  __syncthreads();
  if (t < 8) {
    float s = gb2[t];
#pragma unroll
    for (int w = 0; w < 16; ++w) s += part[w][t];
    Lg[(size_t)tok * 8 + t] = s;
  }
}

// ---------------- single-block router: top2 + prefix + slot assignment (LDS atomics) ----
__global__ __launch_bounds__(1024)
void k_top2assign(const float* __restrict__ Lg, int* __restrict__ counts_g,
                  int* __restrict__ offs_g, int* __restrict__ slot_tok,
                  float* __restrict__ slot_w, int* __restrict__ tok2slot) {
  __shared__ int cnt[NEXP], offs[NEXP], cur[NEXP];
  const int t = threadIdx.x;
  if (t < NEXP) { cnt[t] = 0; cur[t] = 0; }
  __syncthreads();

  int te[4][2]; float tw[4][2];
#pragma unroll
  for (int p = 0; p < 4; ++p) {
    const int tok = p * 1024 + t;
    float l[8];
#pragma unroll
    for (int j = 0; j < 8; ++j) l[j] = Lg[(size_t)tok * 8 + j];
    float mx = l[0];
#pragma unroll
    for (int j = 1; j < 8; ++j) mx = fmaxf(mx, l[j]);
    float pr[8];
#pragma unroll
    for (int j = 0; j < 8; ++j) pr[j] = expf(l[j] - mx);
    int i0 = 0; float b0 = pr[0];
#pragma unroll
    for (int j = 1; j < 8; ++j) if (pr[j] > b0) { b0 = pr[j]; i0 = j; }
    int i1 = (i0 == 0) ? 1 : 0; float b1 = pr[i1];
#pragma unroll
    for (int j = 0; j < 8; ++j) if (j != i0 && pr[j] > b1) { b1 = pr[j]; i1 = j; }
    const float inv = 1.f / (b0 + b1);
    te[p][0] = i0; te[p][1] = i1;
    tw[p][0] = b0 * inv; tw[p][1] = b1 * inv;
    atomicAdd(&cnt[i0], 1);
    atomicAdd(&cnt[i1], 1);
  }
  __syncthreads();
  if (t == 0) {
    int a = 0;
#pragma unroll
    for (int e = 0; e < NEXP; ++e) { offs[e] = a; a += cnt[e]; }
  }
  __syncthreads();
#pragma unroll
  for (int p = 0; p < 4; ++p) {
    const int tok = p * 1024 + t;
#pragma unroll
    for (int k = 0; k < 2; ++k) {
      const int e = te[p][k];
      const int pos = atomicAdd(&cur[e], 1);
      const int s = offs[e] + pos;
      slot_tok[s] = tok;
      slot_w[s] = tw[p][k];
      tok2slot[2 * tok + k] = s;
    }
  }
  if (t < NEXP) { counts_g[t] = cnt[t]; offs_g[t] = offs[t]; }
}

// ---------------- expert GEMM1 (R7 form): H = relu(Xg @ w1) * (Xg @ w3) ----------------
__global__ __launch_bounds__(256, 2)
void k_gemm1(const unsigned short* __restrict__ Xh, const unsigned short* __restrict__ w1T,
             const unsigned short* __restrict__ w3T, const int* __restrict__ slot_tok,
             const int* __restrict__ counts, const int* __restrict__ offs,
             unsigned short* __restrict__ Hout) {
  const int e = blockIdx.z;
  const int cnt = counts[e];
  const int mt = blockIdx.y;
  if (mt * 128 >= cnt) return;
  const int base = offs[e] + mt * 128;
  const int n0 = blockIdx.x * 128;

  __shared__ unsigned short lA[128 * 64];
  __shared__ unsigned short lB1[128 * 64];
  __shared__ unsigned short lB3[128 * 64];
  __shared__ int tokid[128];

  const int t = threadIdx.x;
  if (t < 128) {
    const int s = slot_tok[base + t];
    tokid[t] = ((unsigned)s < TOKENS) ? s : 0;
  }
  __syncthreads();

  const int lane = t & 63, wv = t >> 6;
  const unsigned short *arow[4], *b1row[4], *b3row[4];
#pragma unroll
  for (int i = 0; i < 4; ++i) {
    const int gi = wv * 4 + i;
    const int row = gi * 8 + (lane >> 3);
    const int cs = (lane & 7) ^ (row & 7);
    arow[i] = Xh + (size_t)tokid[row] * HDIM + cs * 8;
    const int f = n0 + row;
    b1row[i] = w1T + ((size_t)e * FDIM + f) * HDIM + cs * 8;
    b3row[i] = w3T + ((size_t)e * FDIM + f) * HDIM + cs * 8;
  }

  f32x4v acc1[4][4], acc3[4][4];
#pragma unroll
  for (int m = 0; m < 4; ++m)
#pragma unroll
    for (int n = 0; n < 4; ++n) {
      acc1[m][n] = (f32x4v){0.f, 0.f, 0.f, 0.f};
      acc3[m][n] = (f32x4v){0.f, 0.f, 0.f, 0.f};
    }
  const int wr = (wv >> 1) * 64, wc = (wv & 1) * 64;

  for (int k0 = 0; k0 < HDIM; k0 += 64) {
#pragma unroll
    for (int i = 0; i < 4; ++i) {
      gload16(lA + (wv * 4 + i) * 512, arow[i] + k0);
      gload16(lB1 + (wv * 4 + i) * 512, b1row[i] + k0);
      gload16(lB3 + (wv * 4 + i) * 512, b3row[i] + k0);
    }
    __syncthreads();
#pragma unroll
    for (int kk = 0; kk < 64; kk += 32) {
      const int ch = (kk >> 3) + (lane >> 4);
      f16x8v af[4];
#pragma unroll
      for (int m = 0; m < 4; ++m) {
        const int r = wr + m * 16 + (lane & 15);
        af[m] = *(const f16x8v*)(lA + r * 64 + (ch ^ (r & 7)) * 8);
      }
#pragma unroll
      for (int n = 0; n < 4; ++n) {
        const int r = wc + n * 16 + (lane & 15);
        const int o = r * 64 + (ch ^ (r & 7)) * 8;
        f16x8v b1 = *(const f16x8v*)(lB1 + o);
        f16x8v b3 = *(const f16x8v*)(lB3 + o);
#pragma unroll
        for (int m = 0; m < 4; ++m) {
          acc1[m][n] = __builtin_amdgcn_mfma_f32_16x16x32_f16(af[m], b1, acc1[m][n], 0, 0, 0);
          acc3[m][n] = __builtin_amdgcn_mfma_f32_16x16x32_f16(af[m], b3, acc3[m][n], 0, 0, 0);
        }
      }
    }
    __syncthreads();
  }

  const int maxr = cnt - mt * 128;
#pragma unroll
  for (int m = 0; m < 4; ++m)
#pragma unroll
    for (int q = 0; q < 4; ++q) {
      const int rl = wr + m * 16 + ((lane >> 4) << 2) + q;
      if (rl < maxr) {
        unsigned short* hrow = Hout + (size_t)(base + rl) * FDIM;
#pragma unroll
        for (int n = 0; n < 4; ++n) {
          const int col = n0 + wc + n * 16 + (lane & 15);
          const float h = fmaxf(acc1[m][n][q], 0.f) * acc3[m][n][q];
          hrow[col] = f2h(h);
        }
      }
    }
}

// ---------------- expert GEMM2 dual-N (R11 form): Y[slot] = H @ w2; BN=256, A shared ----
__global__ __launch_bounds__(256, 2)
void k_gemm2(const unsigned short* __restrict__ Hin, const unsigned short* __restrict__ w2T,
             const int* __restrict__ counts, const int* __restrict__ offs,
             unsigned short* __restrict__ Y) {
  const int e = blockIdx.z;
  const int cnt = counts[e];
  const int mt = blockIdx.y;
  if (mt * 128 >= cnt) return;
  const int base = offs[e] + mt * 128;
  const int n0 = blockIdx.x * 256;

  __shared__ unsigned short lA[128 * 64];
  __shared__ unsigned short lBa[128 * 64];
  __shared__ unsigned short lBb[128 * 64];

  const int t = threadIdx.x, lane = t & 63, wv = t >> 6;
  const unsigned short *arow[4], *browa[4], *browb[4];
#pragma unroll
  for (int i = 0; i < 4; ++i) {
    const int gi = wv * 4 + i;
    const int row = gi * 8 + (lane >> 3);
    const int cs = (lane & 7) ^ (row & 7);
    arow[i] = Hin + (size_t)(base + row) * FDIM + cs * 8;
    browa[i] = w2T + ((size_t)e * HDIM + n0 + row) * FDIM + cs * 8;
    browb[i] = w2T + ((size_t)e * HDIM + n0 + 128 + row) * FDIM + cs * 8;
  }

  f32x4v acca[4][4], accb[4][4];
#pragma unroll
  for (int m = 0; m < 4; ++m)
#pragma unroll
    for (int n = 0; n < 4; ++n) {
      acca[m][n] = (f32x4v){0.f, 0.f, 0.f, 0.f};
      accb[m][n] = (f32x4v){0.f, 0.f, 0.f, 0.f};
    }

  const int wr = (wv >> 1) * 64, wc = (wv & 1) * 64;

  for (int k0 = 0; k0 < FDIM; k0 += 64) {
#pragma unroll
    for (int i = 0; i < 4; ++i) {
      gload16(lA + (wv * 4 + i) * 512, arow[i] + k0);
      gload16(lBa + (wv * 4 + i) * 512, browa[i] + k0);
      gload16(lBb + (wv * 4 + i) * 512, browb[i] + k0);
    }
    __syncthreads();
#pragma unroll
    for (int kk = 0; kk < 64; kk += 32) {
      const int ch = (kk >> 3) + (lane >> 4);
      f16x8v af[4];
#pragma unroll
      for (int m = 0; m < 4; ++m) {
        const int r = wr + m * 16 + (lane & 15);
        af[m] = *(const f16x8v*)(lA + r * 64 + (ch ^ (r & 7)) * 8);
      }
#pragma unroll
      for (int n = 0; n < 4; ++n) {
        const int r = wc + n * 16 + (lane & 15);
        const int o = r * 64 + (ch ^ (r & 7)) * 8;
        f16x8v ba = *(const f16x8v*)(lBa + o);
        f16x8v bb = *(const f16x8v*)(lBb + o);
#pragma unroll
        for (int m = 0; m < 4; ++m) {
          acca[m][n] = __builtin_amdgcn_mfma_f32_16x16x32_f16(af[m], ba, acca[m][n], 0, 0, 0);
          accb[m][n] = __builtin_amdgcn_mfma_f32_16x16x32_f16(af[m], bb, accb[m][n], 0, 0, 0);
        }
      }
    }
    __syncthreads();
  }

  const int maxr = cnt - mt * 128;
#pragma unroll
  for (int m = 0; m < 4; ++m)
#pragma unroll
    for (int q = 0; q < 4; ++q) {
      const int rl = wr + m * 16 + ((lane >> 4) << 2) + q;
      if (rl < maxr) {
        unsigned short* yrow = Y + (size_t)(base + rl) * HDIM;
#pragma unroll
        for (int n = 0; n < 4; ++n) {
          const int col = n0 + wc + n * 16 + (lane & 15);
          yrow[col] = f2h(acca[m][n][q]);
          yrow[col + 128] = f2h(accb[m][n][q]);
        }
      }
    }
}

// ---------------- combine: out[t] = w0*Y[s0] + w1*Y[s1] (Y f16) ----------------
__global__ __launch_bounds__(256)
void k_combine(const unsigned short* __restrict__ Y, const int* __restrict__ tok2slot,
               const float* __restrict__ slot_w, float* __restrict__ out) {
  const int tok = blockIdx.x;
  const int s0 = tok2slot[2 * tok], s1 = tok2slot[2 * tok + 1];
  const float w0 = slot_w[s0], w1 = slot_w[s1];
  const int i = threadIdx.x * 4;
  const _Float16* y0 = (const _Float16*)(Y + (size_t)s0 * HDIM + i);
  const _Float16* y1 = (const _Float16*)(Y + (size_t)s1 * HDIM + i);
  f32x4v r;
#pragma unroll
  for (int j = 0; j < 4; ++j) r[j] = w0 * (float)y0[j] + w1 * (float)y1[j];
  *(f32x4v*)(out + (size_t)tok * HDIM + i) = r;
}

extern "C" void kernel_launch(void* const* d_in, const int* in_sizes, int n_in,
                              void* d_out, int out_size, void* d_ws, size_t ws_size,
                              hipStream_t stream) {
  const float* X   = (const float*)d_in[0];
  const float* gw1 = (const float*)d_in[1];
  const float* gb1 = (const float*)d_in[2];
  const float* gw2 = (const float*)d_in[3];
  const float* gb2 = (const float*)d_in[4];
  const float* w1  = (const float*)d_in[5];
  const float* w3  = (const float*)d_in[6];
  const float* w2  = (const float*)d_in[7];

  float* out = (float*)d_out;
  float* Lg  = out + (size_t)TOKENS * HDIM;

  char* ws = (char*)d_ws;
  size_t off = 0;
  auto alloc = [&](size_t b) { void* p = ws + off; off = (off + b + 255) & ~(size_t)255; return p; };

  unsigned short* Xh    = (unsigned short*)alloc((size_t)TOKENS * HDIM * 2);
  unsigned short* gw1T  = (unsigned short*)alloc((size_t)HDIM * 1024 * 2);
  unsigned short* w1T   = (unsigned short*)alloc((size_t)NEXP * FDIM * HDIM * 2);
  unsigned short* w3T   = (unsigned short*)alloc((size_t)NEXP * FDIM * HDIM * 2);
  unsigned short* w2T   = (unsigned short*)alloc((size_t)NEXP * HDIM * FDIM * 2);
  unsigned short* Gh    = (unsigned short*)alloc((size_t)TOKENS * 1024 * 2);
  unsigned short* Hf    = (unsigned short*)alloc((size_t)SLOTPAD * FDIM * 2);
  unsigned short* Yb    = (unsigned short*)alloc((size_t)SLOTPAD * HDIM * 2);
  int*   tok2slot = (int*)alloc((size_t)TOKENS * 2 * 4);
  int*   counts   = (int*)alloc(64);
  int*   offs     = (int*)alloc(64);
  int*   slot_tok = (int*)alloc((size_t)SLOTPAD * 4);
  float* slot_w   = (float*)alloc((size_t)SLOTPAD * 4);
  int*   risky    = (int*)alloc((size_t)RISKY_CAP * 4);
  int*   rcnt     = (int*)alloc(64);

  k_prep0<<<dim3(257), 256, 0, stream>>>(gw1, gw1T, rcnt);
  k_fused<<<dim3(NB_GATE + NB_W13 + NB_W2), 256, 0, stream>>>(
      X, Xh, w1, w3, w1T, w3T, w2, w2T, gw1T, gb1, Gh);
  k_logits<<<dim3(TOKENS / 4), 256, 0, stream>>>(Gh, gw2, gb2, Lg, risky, rcnt);
  k_fixup<<<dim3(RISKY_CAP), 1024, 0, stream>>>(X, gw1, gb1, gw2, gb2, risky, rcnt, Lg);
  k_top2assign<<<dim3(1), 1024, 0, stream>>>(Lg, counts, offs, slot_tok, slot_w, tok2slot);
  k_gemm1<<<dim3(FDIM / 128, TOKENS / 128, NEXP), 256, 0, stream>>>(Xh, w1T, w3T, slot_tok, counts, offs, Hf);
  k_gemm2<<<dim3(HDIM / 256, TOKENS / 128, NEXP), 256, 0, stream>>>(Hf, w2T, counts, offs, Yb);
  k_combine<<<dim3(TOKENS), 256, 0, stream>>>(Yb, tok2slot, slot_w, out);
}

// Round 16
// 301.173 us; speedup vs baseline: 1.0407x; 1.0407x over previous
//
#include <hip/hip_runtime.h>
#include <hip/hip_bf16.h>
#include <stdint.h>

#define TOKENS 4096
#define HDIM   1024
#define FDIM   2048
#define NEXP   8
#define NSLOTS (2 * TOKENS)
#define SLOTPAD (NSLOTS + 256)
#define RISKY_CAP 256
#define FLAG_THR 6e-3f

typedef __attribute__((ext_vector_type(4))) float        f32x4v;
typedef __attribute__((ext_vector_type(4))) unsigned int u32x4v;
typedef __attribute__((ext_vector_type(8))) _Float16     f16x8v;

__device__ __forceinline__ unsigned short f2h(float f) {
  _Float16 h = (_Float16)f;
  union { _Float16 h; unsigned short u; } x; x.h = h; return x.u;
}

__device__ __forceinline__ void gload16(void* lds, const void* g) {
  __builtin_amdgcn_global_load_lds(
      reinterpret_cast<const __attribute__((address_space(1))) uint32_t*>(
          reinterpret_cast<uintptr_t>(g)),
      reinterpret_cast<__attribute__((address_space(3))) uint32_t*>(
          reinterpret_cast<uintptr_t>(lds)),
      16, 0, 0);
}

// ---------------- transpose tile: [R][C] f32 -> [C][R] f16, one 64x64 tile ----------------
__device__ __forceinline__ void transpose_tile_v2(const float* __restrict__ ip,
                                                  unsigned short* __restrict__ op,
                                                  int R, int C, int r0, int c0) {
  __shared__ unsigned short tile[64][70];
  const int t = threadIdx.x;
  const int cp = (t & 15) * 4;
  const int rp = (t >> 4) * 2;
#pragma unroll
  for (int p = 0; p < 2; ++p) {
    const int r = rp + p * 32;
    f32x4v v0 = *(const f32x4v*)(ip + (size_t)(r0 + r) * C + c0 + cp);
    f32x4v v1 = *(const f32x4v*)(ip + (size_t)(r0 + r + 1) * C + c0 + cp);
#pragma unroll
    for (int j = 0; j < 4; ++j)
      *(uint32_t*)&tile[cp + j][r] = (uint32_t)f2h(v0[j]) | ((uint32_t)f2h(v1[j]) << 16);
  }
  __syncthreads();
  const int c = t >> 2, rc = (t & 3) * 16;
  uint32_t q[8];
#pragma unroll
  for (int j = 0; j < 8; ++j) q[j] = *(uint32_t*)&tile[c][rc + j * 2];
  unsigned short* o = op + (size_t)(c0 + c) * R + r0 + rc;
  u32x4v s0, s1;
  s0[0] = q[0]; s0[1] = q[1]; s0[2] = q[2]; s0[3] = q[3];
  s1[0] = q[4]; s1[1] = q[5]; s1[2] = q[6]; s1[3] = q[7];
  *(u32x4v*)o = s0;
  *(u32x4v*)(o + 8) = s1;
}

// ---------------- prep0: gw1 transpose + zero rcnt ----------------
__global__ __launch_bounds__(256)
void k_prep0(const float* __restrict__ gw1, unsigned short* __restrict__ og1,
             int* __restrict__ rcnt) {
  if (blockIdx.x == 256) {
    if (threadIdx.x == 0) rcnt[0] = 0;
    return;
  }
  transpose_tile_v2(gw1, og1, 1024, 1024, (blockIdx.x >> 4) * 64, (blockIdx.x & 15) * 64);
}

// ---------------- fused: gate GEMM (f32 X in) + X convert + w13/w2 transposes ----------
#define NB_GATE 512
#define NB_CONV 2048
#define NB_W13  8192
#define NB_W2   4096
__global__ __launch_bounds__(256)
void k_fused(const float* __restrict__ X, unsigned short* __restrict__ Xh,
             const float* __restrict__ w1, const float* __restrict__ w3,
             unsigned short* __restrict__ o1, unsigned short* __restrict__ o3,
             const float* __restrict__ w2, unsigned short* __restrict__ o2,
             const unsigned short* __restrict__ gw1T, const float* __restrict__ gb1,
             unsigned short* __restrict__ Gh) {
  const int id = blockIdx.x;
  const int t = threadIdx.x;
  if (id < NB_GATE) {
    __shared__ unsigned short lA[128 * 64];
    __shared__ unsigned short lB[64 * 64];
    const int n0 = (id & 15) * 64, m0 = (id >> 4) * 128;
    const int lane = t & 63, wv = t >> 6;

    const unsigned short* bp[2];
#pragma unroll
    for (int i = 0; i < 2; ++i) {
      const int gi = wv * 2 + i;
      const int row = gi * 8 + (lane >> 3);
      const int cs = (lane & 7) ^ (row & 7);
      bp[i] = gw1T + (size_t)(n0 + row) * HDIM + cs * 8;
    }

    f32x4v acc[4][2];
#pragma unroll
    for (int m = 0; m < 4; ++m)
#pragma unroll
      for (int n = 0; n < 2; ++n) acc[m][n] = (f32x4v){0.f, 0.f, 0.f, 0.f};

    const int wr = (wv >> 1) * 64, wc = (wv & 1) * 32;

    for (int k0 = 0; k0 < HDIM; k0 += 64) {
#pragma unroll
      for (int p = 0; p < 4; ++p) {
        const int ga = p * 256 + t;
        const int r = ga >> 3, c = ga & 7;
        const float* s = X + (size_t)(m0 + r) * HDIM + k0 + c * 8;
        f32x4v v0 = *(const f32x4v*)s;
        f32x4v v1 = *(const f32x4v*)(s + 4);
        u32x4v pk;
        pk[0] = (uint32_t)f2h(v0[0]) | ((uint32_t)f2h(v0[1]) << 16);
        pk[1] = (uint32_t)f2h(v0[2]) | ((uint32_t)f2h(v0[3]) << 16);
        pk[2] = (uint32_t)f2h(v1[0]) | ((uint32_t)f2h(v1[1]) << 16);
        pk[3] = (uint32_t)f2h(v1[2]) | ((uint32_t)f2h(v1[3]) << 16);
        *(u32x4v*)&lA[r * 64 + ((c ^ (r & 7)) * 8)] = pk;
      }
#pragma unroll
      for (int i = 0; i < 2; ++i) gload16(lB + (wv * 2 + i) * 512, bp[i] + k0);
      __syncthreads();
#pragma unroll
      for (int kk = 0; kk < 2; ++kk) {
        const int ch = kk * 4 + (lane >> 4);
        f16x8v af[4];
#pragma unroll
        for (int m = 0; m < 4; ++m) {
          const int r = wr + m * 16 + (lane & 15);
          af[m] = *(const f16x8v*)(lA + r * 64 + (ch ^ (r & 7)) * 8);
        }
#pragma unroll
        for (int n = 0; n < 2; ++n) {
          const int r = wc + n * 16 + (lane & 15);
          f16x8v b = *(const f16x8v*)(lB + r * 64 + (ch ^ (r & 7)) * 8);
#pragma unroll
          for (int m = 0; m < 4; ++m)
            acc[m][n] = __builtin_amdgcn_mfma_f32_16x16x32_f16(af[m], b, acc[m][n], 0, 0, 0);
        }
      }
      __syncthreads();
    }
#pragma unroll
    for (int m = 0; m < 4; ++m)
#pragma unroll
      for (int n = 0; n < 2; ++n)
#pragma unroll
        for (int q = 0; q < 4; ++q) {
          const int row = m0 + wr + m * 16 + ((lane >> 4) << 2) + q;
          const int col = n0 + wc + n * 16 + (lane & 15);
          float x = acc[m][n][q] + gb1[col];
          Gh[(size_t)row * 1024 + col] = f2h(x > 0.f ? x : expm1f(x));
        }
    return;
  }
  int b = id - NB_GATE;
  if (b < NB_CONV) {
    const int i = (b * 256 + t) * 8;
    f32x4v a = *(const f32x4v*)(X + i);
    f32x4v c = *(const f32x4v*)(X + i + 4);
    u32x4v r;
    r[0] = (uint32_t)f2h(a[0]) | ((uint32_t)f2h(a[1]) << 16);
    r[1] = (uint32_t)f2h(a[2]) | ((uint32_t)f2h(a[3]) << 16);
    r[2] = (uint32_t)f2h(c[0]) | ((uint32_t)f2h(c[1]) << 16);
    r[3] = (uint32_t)f2h(c[2]) | ((uint32_t)f2h(c[3]) << 16);
    *(u32x4v*)(Xh + i) = r;
    return;
  }
  b -= NB_CONV;
  if (b < NB_W13) {
    const int bx = b & 31, by = (b >> 5) & 15, bz = b >> 9;
    const int e = bz & 7, which = bz >> 3;
    const size_t mat = (size_t)1024 * 2048;
    transpose_tile_v2((which ? w3 : w1) + (size_t)e * mat,
                      (which ? o3 : o1) + (size_t)e * mat,
                      1024, 2048, by * 64, bx * 64);
    return;
  }
  b -= NB_W13;
  {
    const int bx = b & 15, by = (b >> 4) & 31, e = b >> 9;
    const size_t mat = (size_t)2048 * 1024;
    transpose_tile_v2(w2 + (size_t)e * mat, o2 + (size_t)e * mat,
                      2048, 1024, by * 64, bx * 64);
  }
}

// ---------------- router logits (fp32 accum over f16 G) + fused risk flag ----------------
__global__ void k_logits(const unsigned short* __restrict__ Gh, const float* __restrict__ gw2,
                         const float* __restrict__ gb2, float* __restrict__ Lg,
                         int* __restrict__ risky, int* __restrict__ rcnt) {
  const int lane = threadIdx.x & 63, wv = threadIdx.x >> 6;
  const int tok = blockIdx.x * 4 + wv;
  const unsigned short* g = Gh + (size_t)tok * 1024 + lane * 16;
  f16x8v g0 = *(const f16x8v*)g;
  f16x8v g1 = *(const f16x8v*)(g + 8);
  float gv[16];
#pragma unroll
  for (int j = 0; j < 8; ++j) { gv[j] = (float)g0[j]; gv[8 + j] = (float)g1[j]; }
  float acc[8];
#pragma unroll
  for (int j = 0; j < 8; ++j) acc[j] = 0.f;
#pragma unroll
  for (int u = 0; u < 16; ++u) {
    const float* wrow = gw2 + (size_t)(lane * 16 + u) * 8;
    f32x4v w0 = *(const f32x4v*)wrow;
    f32x4v w1 = *(const f32x4v*)(wrow + 4);
#pragma unroll
    for (int j = 0; j < 4; ++j) {
      acc[j]     += gv[u] * w0[j];
      acc[j + 4] += gv[u] * w1[j];
    }
  }
#pragma unroll
  for (int s = 1; s < 64; s <<= 1)
#pragma unroll
    for (int j = 0; j < 8; ++j) acc[j] += __shfl_xor(acc[j], s, 64);
  if (lane == 0) {
    float l[8];
#pragma unroll
    for (int j = 0; j < 8; ++j) { l[j] = acc[j] + gb2[j]; Lg[(size_t)tok * 8 + j] = l[j]; }
    int i0 = 0; float v0 = l[0];
#pragma unroll
    for (int j = 1; j < 8; ++j) if (l[j] > v0) { v0 = l[j]; i0 = j; }
    int i1 = (i0 == 0) ? 1 : 0; float v1 = l[i1];
#pragma unroll
    for (int j = 0; j < 8; ++j) if (j != i0 && l[j] > v1) { v1 = l[j]; i1 = j; }
    float v2 = -1e30f;
#pragma unroll
    for (int j = 0; j < 8; ++j) if (j != i0 && j != i1 && l[j] > v2) v2 = l[j];
    if (v1 - v2 < FLAG_THR) {
      const int pos = atomicAdd(rcnt, 1);
      if (pos < RISKY_CAP) risky[pos] = tok;
    }
  }
}

// ---------------- fixup phase 1: exact fp32 gate hidden for risky tokens ----------------
__global__ __launch_bounds__(256)
void k_fixup_gs(const float* __restrict__ X, const float* __restrict__ gw1,
                const float* __restrict__ gb1, const int* __restrict__ risky,
                const int* __restrict__ rcnt, float* __restrict__ gsbuf) {
  __shared__ float xs[1024];
  __shared__ float red[128];
  int n = *rcnt; if (n > RISKY_CAP) n = RISKY_CAP;
  const int idx = blockIdx.y;
  if (idx >= n) return;
  const int tok = risky[idx];
  const int s0 = blockIdx.x * 128;
  const int t = threadIdx.x;
  for (int i = t; i < 1024; i += 256) xs[i] = X[(size_t)tok * 1024 + i];
  __syncthreads();
  const int h = t & 127, kh = t >> 7;
  const float* wp = gw1 + (size_t)(kh * 512) * 1024 + s0 + h;
  const float* xp = xs + kh * 512;
  float a0 = 0.f, a1 = 0.f, a2 = 0.f, a3 = 0.f;
  for (int k = 0; k < 512; k += 4) {
    a0 += xp[k]     * wp[(size_t)k * 1024];
    a1 += xp[k + 1] * wp[(size_t)(k + 1) * 1024];
    a2 += xp[k + 2] * wp[(size_t)(k + 2) * 1024];
    a3 += xp[k + 3] * wp[(size_t)(k + 3) * 1024];
  }
  const float acc = (a0 + a1) + (a2 + a3);
  if (kh == 1) red[h] = acc;
  __syncthreads();
  if (kh == 0) {
    const float v = acc + red[h] + gb1[s0 + h];
    gsbuf[(size_t)idx * 1024 + s0 + h] = v > 0.f ? v : expm1f(v);
  }
}

// ---------------- fixup phase 2: exact fp32 logits for risky tokens ----------------
__global__ __launch_bounds__(256)
void k_fixup_lg(const float* __restrict__ gsbuf, const float* __restrict__ gw2,
                const float* __restrict__ gb2, const int* __restrict__ risky,
                const int* __restrict__ rcnt, float* __restrict__ Lg) {
  __shared__ float part[4][8];
  int n = *rcnt; if (n > RISKY_CAP) n = RISKY_CAP;
  const int idx = blockIdx.x;
  if (idx >= n) return;
  const int tok = risky[idx];
  const int t = threadIdx.x, lane = t & 63, wv = t >> 6;
  float lacc[8];
#pragma unroll
  for (int e = 0; e < 8; ++e) lacc[e] = 0.f;
#pragma unroll
  for (int j = 0; j < 4; ++j) {
    const int k = t * 4 + j;
    const float gv = gsbuf[(size_t)idx * 1024 + k];
    const float* w = gw2 + (size_t)k * 8;
#pragma unroll
    for (int e = 0; e < 8; ++e) lacc[e] += gv * w[e];
  }
#pragma unroll
  for (int s = 1; s < 64; s <<= 1)
#pragma unroll
    for (int e = 0; e < 8; ++e) lacc[e] += __shfl_xor(lacc[e], s, 64);
  if (lane == 0) {
#pragma unroll
    for (int e = 0; e < 8; ++e) part[wv][e] = lacc[e];
  }
  __syncthreads();
  if (t < 8) Lg[(size_t)tok * 8 + t] = part[0][t] + part[1][t] + part[2][t] + part[3][t] + gb2[t];
}

// ---------------- single-block router: top2 + prefix + slot assignment (LDS atomics) ----
__global__ __launch_bounds__(1024)
void k_top2assign(const float* __restrict__ Lg, int* __restrict__ counts_g,
                  int* __restrict__ offs_g, int* __restrict__ slot_tok,
                  float* __restrict__ slot_w, int* __restrict__ tok2slot) {
  __shared__ int cnt[NEXP], offs[NEXP], cur[NEXP];
  const int t = threadIdx.x;
  if (t < NEXP) { cnt[t] = 0; cur[t] = 0; }
  __syncthreads();

  int te[4][2]; float tw[4][2];
#pragma unroll
  for (int p = 0; p < 4; ++p) {
    const int tok = p * 1024 + t;
    float l[8];
#pragma unroll
    for (int j = 0; j < 8; ++j) l[j] = Lg[(size_t)tok * 8 + j];
    float mx = l[0];
#pragma unroll
    for (int j = 1; j < 8; ++j) mx = fmaxf(mx, l[j]);
    float pr[8];
#pragma unroll
    for (int j = 0; j < 8; ++j) pr[j] = expf(l[j] - mx);
    int i0 = 0; float b0 = pr[0];
#pragma unroll
    for (int j = 1; j < 8; ++j) if (pr[j] > b0) { b0 = pr[j]; i0 = j; }
    int i1 = (i0 == 0) ? 1 : 0; float b1 = pr[i1];
#pragma unroll
    for (int j = 0; j < 8; ++j) if (j != i0 && pr[j] > b1) { b1 = pr[j]; i1 = j; }
    const float inv = 1.f / (b0 + b1);
    te[p][0] = i0; te[p][1] = i1;
    tw[p][0] = b0 * inv; tw[p][1] = b1 * inv;
    atomicAdd(&cnt[i0], 1);
    atomicAdd(&cnt[i1], 1);
  }
  __syncthreads();
  if (t == 0) {
    int a = 0;
#pragma unroll
    for (int e = 0; e < NEXP; ++e) { offs[e] = a; a += cnt[e]; }
  }
  __syncthreads();
#pragma unroll
  for (int p = 0; p < 4; ++p) {
    const int tok = p * 1024 + t;
#pragma unroll
    for (int k = 0; k < 2; ++k) {
      const int e = te[p][k];
      const int pos = atomicAdd(&cur[e], 1);
      const int s = offs[e] + pos;
      slot_tok[s] = tok;
      slot_w[s] = tw[p][k];
      tok2slot[2 * tok + k] = s;
    }
  }
  if (t < NEXP) { counts_g[t] = cnt[t]; offs_g[t] = offs[t]; }
}

// ---------------- expert GEMM1 (R7 form): H = relu(Xg @ w1) * (Xg @ w3) ----------------
__global__ __launch_bounds__(256, 2)
void k_gemm1(const unsigned short* __restrict__ Xh, const unsigned short* __restrict__ w1T,
             const unsigned short* __restrict__ w3T, const int* __restrict__ slot_tok,
             const int* __restrict__ counts, const int* __restrict__ offs,
             unsigned short* __restrict__ Hout) {
  const int e = blockIdx.z;
  const int cnt = counts[e];
  const int mt = blockIdx.y;
  if (mt * 128 >= cnt) return;
  const int base = offs[e] + mt * 128;
  const int n0 = blockIdx.x * 128;

  __shared__ unsigned short lA[128 * 64];
  __shared__ unsigned short lB1[128 * 64];
  __shared__ unsigned short lB3[128 * 64];
  __shared__ int tokid[128];

  const int t = threadIdx.x;
  if (t < 128) {
    const int s = slot_tok[base + t];
    tokid[t] = ((unsigned)s < TOKENS) ? s : 0;
  }
  __syncthreads();

  const int lane = t & 63, wv = t >> 6;
  const unsigned short *arow[4], *b1row[4], *b3row[4];
#pragma unroll
  for (int i = 0; i < 4; ++i) {
    const int gi = wv * 4 + i;
    const int row = gi * 8 + (lane >> 3);
    const int cs = (lane & 7) ^ (row & 7);
    arow[i] = Xh + (size_t)tokid[row] * HDIM + cs * 8;
    const int f = n0 + row;
    b1row[i] = w1T + ((size_t)e * FDIM + f) * HDIM + cs * 8;
    b3row[i] = w3T + ((size_t)e * FDIM + f) * HDIM + cs * 8;
  }

  f32x4v acc1[4][4], acc3[4][4];
#pragma unroll
  for (int m = 0; m < 4; ++m)
#pragma unroll
    for (int n = 0; n < 4; ++n) {
      acc1[m][n] = (f32x4v){0.f, 0.f, 0.f, 0.f};
      acc3[m][n] = (f32x4v){0.f, 0.f, 0.f, 0.f};
    }
  const int wr = (wv >> 1) * 64, wc = (wv & 1) * 64;

  for (int k0 = 0; k0 < HDIM; k0 += 64) {
#pragma unroll
    for (int i = 0; i < 4; ++i) {
      gload16(lA + (wv * 4 + i) * 512, arow[i] + k0);
      gload16(lB1 + (wv * 4 + i) * 512, b1row[i] + k0);
      gload16(lB3 + (wv * 4 + i) * 512, b3row[i] + k0);
    }
    __syncthreads();
#pragma unroll
    for (int kk = 0; kk < 64; kk += 32) {
      const int ch = (kk >> 3) + (lane >> 4);
      f16x8v af[4];
#pragma unroll
      for (int m = 0; m < 4; ++m) {
        const int r = wr + m * 16 + (lane & 15);
        af[m] = *(const f16x8v*)(lA + r * 64 + (ch ^ (r & 7)) * 8);
      }
#pragma unroll
      for (int n = 0; n < 4; ++n) {
        const int r = wc + n * 16 + (lane & 15);
        const int o = r * 64 + (ch ^ (r & 7)) * 8;
        f16x8v b1 = *(const f16x8v*)(lB1 + o);
        f16x8v b3 = *(const f16x8v*)(lB3 + o);
#pragma unroll
        for (int m = 0; m < 4; ++m) {
          acc1[m][n] = __builtin_amdgcn_mfma_f32_16x16x32_f16(af[m], b1, acc1[m][n], 0, 0, 0);
          acc3[m][n] = __builtin_amdgcn_mfma_f32_16x16x32_f16(af[m], b3, acc3[m][n], 0, 0, 0);
        }
      }
    }
    __syncthreads();
  }

  const int maxr = cnt - mt * 128;
#pragma unroll
  for (int m = 0; m < 4; ++m)
#pragma unroll
    for (int q = 0; q < 4; ++q) {
      const int rl = wr + m * 16 + ((lane >> 4) << 2) + q;
      if (rl < maxr) {
        unsigned short* hrow = Hout + (size_t)(base + rl) * FDIM;
#pragma unroll
        for (int n = 0; n < 4; ++n) {
          const int col = n0 + wc + n * 16 + (lane & 15);
          const float h = fmaxf(acc1[m][n][q], 0.f) * acc3[m][n][q];
          hrow[col] = f2h(h);
        }
      }
    }
}

// ---------------- expert GEMM2 dual-N (R11 form): Y[slot] = H @ w2; BN=256, A shared ----
__global__ __launch_bounds__(256, 2)
void k_gemm2(const unsigned short* __restrict__ Hin, const unsigned short* __restrict__ w2T,
             const int* __restrict__ counts, const int* __restrict__ offs,
             unsigned short* __restrict__ Y) {
  const int e = blockIdx.z;
  const int cnt = counts[e];
  const int mt = blockIdx.y;
  if (mt * 128 >= cnt) return;
  const int base = offs[e] + mt * 128;
  const int n0 = blockIdx.x * 256;

  __shared__ unsigned short lA[128 * 64];
  __shared__ unsigned short lBa[128 * 64];
  __shared__ unsigned short lBb[128 * 64];

  const int t = threadIdx.x, lane = t & 63, wv = t >> 6;
  const unsigned short *arow[4], *browa[4], *browb[4];
#pragma unroll
  for (int i = 0; i < 4; ++i) {
    const int gi = wv * 4 + i;
    const int row = gi * 8 + (lane >> 3);
    const int cs = (lane & 7) ^ (row & 7);
    arow[i] = Hin + (size_t)(base + row) * FDIM + cs * 8;
    browa[i] = w2T + ((size_t)e * HDIM + n0 + row) * FDIM + cs * 8;
    browb[i] = w2T + ((size_t)e * HDIM + n0 + 128 + row) * FDIM + cs * 8;
  }

  f32x4v acca[4][4], accb[4][4];
#pragma unroll
  for (int m = 0; m < 4; ++m)
#pragma unroll
    for (int n = 0; n < 4; ++n) {
      acca[m][n] = (f32x4v){0.f, 0.f, 0.f, 0.f};
      accb[m][n] = (f32x4v){0.f, 0.f, 0.f, 0.f};
    }

  const int wr = (wv >> 1) * 64, wc = (wv & 1) * 64;

  for (int k0 = 0; k0 < FDIM; k0 += 64) {
#pragma unroll
    for (int i = 0; i < 4; ++i) {
      gload16(lA + (wv * 4 + i) * 512, arow[i] + k0);
      gload16(lBa + (wv * 4 + i) * 512, browa[i] + k0);
      gload16(lBb + (wv * 4 + i) * 512, browb[i] + k0);
    }
    __syncthreads();
#pragma unroll
    for (int kk = 0; kk < 64; kk += 32) {
      const int ch = (kk >> 3) + (lane >> 4);
      f16x8v af[4];
#pragma unroll
      for (int m = 0; m < 4; ++m) {
        const int r = wr + m * 16 + (lane & 15);
        af[m] = *(const f16x8v*)(lA + r * 64 + (ch ^ (r & 7)) * 8);
      }
#pragma unroll
      for (int n = 0; n < 4; ++n) {
        const int r = wc + n * 16 + (lane & 15);
        const int o = r * 64 + (ch ^ (r & 7)) * 8;
        f16x8v ba = *(const f16x8v*)(lBa + o);
        f16x8v bb = *(const f16x8v*)(lBb + o);
#pragma unroll
        for (int m = 0; m < 4; ++m) {
          acca[m][n] = __builtin_amdgcn_mfma_f32_16x16x32_f16(af[m], ba, acca[m][n], 0, 0, 0);
          accb[m][n] = __builtin_amdgcn_mfma_f32_16x16x32_f16(af[m], bb, accb[m][n], 0, 0, 0);
        }
      }
    }
    __syncthreads();
  }

  const int maxr = cnt - mt * 128;
#pragma unroll
  for (int m = 0; m < 4; ++m)
#pragma unroll
    for (int q = 0; q < 4; ++q) {
      const int rl = wr + m * 16 + ((lane >> 4) << 2) + q;
      if (rl < maxr) {
        unsigned short* yrow = Y + (size_t)(base + rl) * HDIM;
#pragma unroll
        for (int n = 0; n < 4; ++n) {
          const int col = n0 + wc + n * 16 + (lane & 15);
          yrow[col] = f2h(acca[m][n][q]);
          yrow[col + 128] = f2h(accb[m][n][q]);
        }
      }
    }
}

// ---------------- combine: out[t] = w0*Y[s0] + w1*Y[s1] (Y f16) ----------------
__global__ __launch_bounds__(256)
void k_combine(const unsigned short* __restrict__ Y, const int* __restrict__ tok2slot,
               const float* __restrict__ slot_w, float* __restrict__ out) {
  const int tok = blockIdx.x;
  const int s0 = tok2slot[2 * tok], s1 = tok2slot[2 * tok + 1];
  const float w0 = slot_w[s0], w1 = slot_w[s1];
  const int i = threadIdx.x * 4;
  const _Float16* y0 = (const _Float16*)(Y + (size_t)s0 * HDIM + i);
  const _Float16* y1 = (const _Float16*)(Y + (size_t)s1 * HDIM + i);
  f32x4v r;
#pragma unroll
  for (int j = 0; j < 4; ++j) r[j] = w0 * (float)y0[j] + w1 * (float)y1[j];
  *(f32x4v*)(out + (size_t)tok * HDIM + i) = r;
}

extern "C" void kernel_launch(void* const* d_in, const int* in_sizes, int n_in,
                              void* d_out, int out_size, void* d_ws, size_t ws_size,
                              hipStream_t stream) {
  const float* X   = (const float*)d_in[0];
  const float* gw1 = (const float*)d_in[1];
  const float* gb1 = (const float*)d_in[2];
  const float* gw2 = (const float*)d_in[3];
  const float* gb2 = (const float*)d_in[4];
  const float* w1  = (const float*)d_in[5];
  const float* w3  = (const float*)d_in[6];
  const float* w2  = (const float*)d_in[7];

  float* out = (float*)d_out;
  float* Lg  = out + (size_t)TOKENS * HDIM;

  char* ws = (char*)d_ws;
  size_t off = 0;
  auto alloc = [&](size_t b) { void* p = ws + off; off = (off + b + 255) & ~(size_t)255; return p; };

  unsigned short* Xh    = (unsigned short*)alloc((size_t)TOKENS * HDIM * 2);
  unsigned short* gw1T  = (unsigned short*)alloc((size_t)HDIM * 1024 * 2);
  unsigned short* w1T   = (unsigned short*)alloc((size_t)NEXP * FDIM * HDIM * 2);
  unsigned short* w3T   = (unsigned short*)alloc((size_t)NEXP * FDIM * HDIM * 2);
  unsigned short* w2T   = (unsigned short*)alloc((size_t)NEXP * HDIM * FDIM * 2);
  unsigned short* Gh    = (unsigned short*)alloc((size_t)TOKENS * 1024 * 2);
  unsigned short* Hf    = (unsigned short*)alloc((size_t)SLOTPAD * FDIM * 2);
  unsigned short* Yb    = (unsigned short*)alloc((size_t)SLOTPAD * HDIM * 2);
  float*          gsbuf = (float*)alloc((size_t)RISKY_CAP * 1024 * 4);
  int*   tok2slot = (int*)alloc((size_t)TOKENS * 2 * 4);
  int*   counts   = (int*)alloc(64);
  int*   offs     = (int*)alloc(64);
  int*   slot_tok = (int*)alloc((size_t)SLOTPAD * 4);
  float* slot_w   = (float*)alloc((size_t)SLOTPAD * 4);
  int*   risky    = (int*)alloc((size_t)RISKY_CAP * 4);
  int*   rcnt     = (int*)alloc(64);

  k_prep0<<<dim3(257), 256, 0, stream>>>(gw1, gw1T, rcnt);
  k_fused<<<dim3(NB_GATE + NB_CONV + NB_W13 + NB_W2), 256, 0, stream>>>(
      X, Xh, w1, w3, w1T, w3T, w2, w2T, gw1T, gb1, Gh);
  k_logits<<<dim3(TOKENS / 4), 256, 0, stream>>>(Gh, gw2, gb2, Lg, risky, rcnt);
  k_fixup_gs<<<dim3(8, RISKY_CAP), 256, 0, stream>>>(X, gw1, gb1, risky, rcnt, gsbuf);
  k_fixup_lg<<<dim3(RISKY_CAP), 256, 0, stream>>>(gsbuf, gw2, gb2, risky, rcnt, Lg);
  k_top2assign<<<dim3(1), 1024, 0, stream>>>(Lg, counts, offs, slot_tok, slot_w, tok2slot);
  k_gemm1<<<dim3(FDIM / 128, TOKENS / 128, NEXP), 256, 0, stream>>>(Xh, w1T, w3T, slot_tok, counts, offs, Hf);
  k_gemm2<<<dim3(HDIM / 256, TOKENS / 128, NEXP), 256, 0, stream>>>(Hf, w2T, counts, offs, Yb);
  k_combine<<<dim3(TOKENS), 256, 0, stream>>>(Yb, tok2slot, slot_w, out);
}